// Round 1
// baseline (467.820 us; speedup 1.0000x reference)
//
#include <hip/hip_runtime.h>

#define RES 256
#define NV 6890
#define KWIN 343                      // 7^3 offsets
#define SEM_ELEMS (RES*RES*RES*3)     // 50331648 floats
#define WSUM_ELEMS (RES*RES*RES)      // 16777216 floats

// ---------------------------------------------------------------------------
// Kernel 1: initialize output. sem = 0, wsum = 0.001. Vectorized float4
// stores, grid-stride. Both regions are float4-aligned (sizes % 4 == 0).
// ---------------------------------------------------------------------------
__global__ void svox_init_kernel(float4* __restrict__ out) {
    const int total = (SEM_ELEMS + WSUM_ELEMS) / 4;   // 16777216 float4
    const int semq  = SEM_ELEMS / 4;                  // 12582912 float4
    const float4 z  = make_float4(0.f, 0.f, 0.f, 0.f);
    const float4 w  = make_float4(0.001f, 0.001f, 0.001f, 0.001f);
    int stride = gridDim.x * blockDim.x;
    for (int i = blockIdx.x * blockDim.x + threadIdx.x; i < total; i += stride) {
        out[i] = (i < semq) ? z : w;
    }
}

// ---------------------------------------------------------------------------
// Kernel 2: Gaussian splat. One thread per (vertex, offset) pair.
//   pos = (v + 0.5) * 256 ; center = floor(pos)
//   voxel center (i+0.5)/256 - 0.5 ; w = exp(-d2 * 8192)
// Skip OOB / occ==0 (their reference contribution is exactly 0).
// 4 float atomics per surviving pair.
// ---------------------------------------------------------------------------
__global__ void __launch_bounds__(256)
svox_splat_kernel(const float* __restrict__ verts,
                  const float* __restrict__ codes,
                  const float* __restrict__ occ,
                  float* __restrict__ sem,
                  float* __restrict__ wsum) {
    int i = blockIdx.x * blockDim.x + threadIdx.x;
    const int total = NV * KWIN;
    if (i >= total) return;

    int n = i / KWIN;
    int k = i - n * KWIN;

    float vx = verts[3 * n + 0];
    float vy = verts[3 * n + 1];
    float vz = verts[3 * n + 2];

    // voxel units: pos = (v + 0.5*H)/vs with H=1, vs=1/256
    int cx = (int)floorf((vx + 0.5f) * 256.0f);
    int cy = (int)floorf((vy + 0.5f) * 256.0f);
    int cz = (int)floorf((vz + 0.5f) * 256.0f);

    int ox = k / 49;
    int rem = k - ox * 49;
    int oy = rem / 7;
    int oz = rem - oy * 7;

    int ix = cx + ox - 3;
    int iy = cy + oy - 3;
    int iz = cz + oz - 3;

    if ((unsigned)ix >= (unsigned)RES ||
        (unsigned)iy >= (unsigned)RES ||
        (unsigned)iz >= (unsigned)RES) return;

    int lin = (ix * RES + iy) * RES + iz;

    if (occ[lin] <= 0.0f) return;

    const float inv_res = 1.0f / 256.0f;
    float dx = ((float)ix + 0.5f) * inv_res - 0.5f - vx;
    float dy = ((float)iy + 0.5f) * inv_res - 0.5f - vy;
    float dz = ((float)iz + 0.5f) * inv_res - 0.5f - vz;
    float d2 = dx * dx + dy * dy + dz * dz;

    // 2*sigma^2 = 2/(128^2) = 1/8192
    float w = __expf(-d2 * 8192.0f);

    float c0 = codes[3 * n + 0];
    float c1 = codes[3 * n + 1];
    float c2 = codes[3 * n + 2];

    atomicAdd(&sem[3 * lin + 0], w * c0);
    atomicAdd(&sem[3 * lin + 1], w * c1);
    atomicAdd(&sem[3 * lin + 2], w * c2);
    atomicAdd(&wsum[lin], w);
}

extern "C" void kernel_launch(void* const* d_in, const int* in_sizes, int n_in,
                              void* d_out, int out_size, void* d_ws, size_t ws_size,
                              hipStream_t stream) {
    const float* verts = (const float*)d_in[0];   // (6890,3) f32
    const float* codes = (const float*)d_in[1];   // (6890,3) f32
    const float* occ   = (const float*)d_in[2];   // (256,256,256) f32
    // d_in[3] = smpl_faces (unused)

    float* sem  = (float*)d_out;                  // (256,256,256,3)
    float* wsum = (float*)d_out + SEM_ELEMS;      // (256,256,256)

    // Init: 16.7M float4 stores, grid-stride with 2048 blocks.
    svox_init_kernel<<<2048, 256, 0, stream>>>((float4*)d_out);

    // Splat: one thread per (vertex, offset) pair.
    const int total = NV * KWIN;                  // 2,363,270
    int blocks = (total + 255) / 256;
    svox_splat_kernel<<<blocks, 256, 0, stream>>>(verts, codes, occ, sem, wsum);
}